// Round 3
// baseline (333.160 us; speedup 1.0000x reference)
//
#include <hip/hip_runtime.h>
#include <stdint.h>

// ---------------- problem constants ----------------
#define BM 64            // rows per block
#define NTT 44           // n-tiles of 16 (N padded 700 -> 704)
#define KSTEPS 43        // extended K 1376 / 32
#define KE 1376          // 700 word + 350 pos-onehot + 315 dep-onehot + 1 bias + 10 pad
#define H3S 360          // h3 half-buffer row stride (ushorts); 720B, 16B-aligned
#define OUTC 93
#define KS2 22           // second-gemm k-steps (704/32)

typedef __attribute__((ext_vector_type(8))) short bf16x8;
typedef __attribute__((ext_vector_type(4))) float f32x4;

// ws layout (bytes)
#define O_WB   0
#define SZ_WB  (KSTEPS*NTT*64*8*2)          // 3,874,816
#define O_WOP  (O_WB + SZ_WB)
#define SZ_WOP (KS2*6*64*8*2)               // 270,336

__device__ __forceinline__ unsigned short f2bf(float f) {
  unsigned u = __float_as_uint(f);
  u += 0x7FFFu + ((u >> 16) & 1u);          // RNE
  return (unsigned short)(u >> 16);
}

// ---- prep: pack f32 [Ksrc x Nsrc] into MFMA B-fragment layout [ks][nt][lane][8]
__global__ void pack_w(const float* __restrict__ W, unsigned short* __restrict__ out,
                       int Ksrc, int Nsrc, int ntiles) {
  int blk = blockIdx.x;
  int ks = blk / ntiles, nt = blk - ks*ntiles;
  int l = threadIdx.x;
  int n = nt*16 + (l & 15);
  int k0 = ks*32 + ((l >> 4) << 3);
  unsigned short v[8];
#pragma unroll
  for (int j = 0; j < 8; ++j) {
    int k = k0 + j;
    float f = (k < Ksrc && n < Nsrc) ? W[k*Nsrc + n] : 0.f;
    v[j] = f2bf(f);
  }
  ((uint4*)out)[blk*64 + l] = *(const uint4*)v;
}

// ---- prep: build extended-B (WB) in fragment layout.
// rows 0-699: Ww ; 700+t*50+p: dot(pos_table[p], Wp_t) ; 1050+t*45+d: dot(dep_table[d], Wd_t)
// row 1365: bw+bp+bd ; else 0.  grid = 43*11 blocks x 256 threads (4 n-tiles/block).
__global__ void build_WB(const float* __restrict__ Ww, const float* __restrict__ Wp,
                         const float* __restrict__ Wd, const float* __restrict__ pos_table,
                         const float* __restrict__ dep_table, const float* __restrict__ bw,
                         const float* __restrict__ bp, const float* __restrict__ bd,
                         unsigned short* __restrict__ out) {
  int blk = blockIdx.x;
  int ks = blk / 11, q = blk - ks*11;
  int l = threadIdx.x & 63;
  int nt = q*4 + (threadIdx.x >> 6);
  int n = nt*16 + (l & 15);
  int k0 = ks*32 + ((l >> 4) << 3);
  unsigned short v[8];
#pragma unroll
  for (int j = 0; j < 8; ++j) {
    int k = k0 + j;
    float val = 0.f;
    if (n < 700) {
      if (k < 700) {
        val = Ww[k*700 + n];
      } else if (k < 1050) {
        int u = k - 700; int t = u/50; int p = u - t*50;
        const float* tr = pos_table + p*100;
        const float* wc = Wp + (t*100)*700 + n;
        float a = 0.f;
#pragma unroll 4
        for (int d = 0; d < 100; ++d) a += tr[d] * wc[d*700];
        val = a;
      } else if (k < 1365) {
        int u = k - 1050; int t = u/45; int dd = u - t*45;
        const float* tr = dep_table + dd*100;
        const float* wc = Wd + (t*100)*700 + n;
        float a = 0.f;
#pragma unroll 4
        for (int d = 0; d < 100; ++d) a += tr[d] * wc[d*700];
        val = a;
      } else if (k == 1365) {
        val = bw[n] + bp[n] + bd[n];
      }
    }
    v[j] = f2bf(val);
  }
  ((uint4*)out)[(ks*NTT + nt)*64 + l] = *(const uint4*)v;
}

// ---------------- main fused kernel ----------------
struct SMem {
  union {
    struct { unsigned short A[4*64*8]; unsigned short B[NTT*64*8]; } mm;  // 49,152 B
    unsigned short h3h[64*H3S];                                           // 46,080 B (logits alias)
  } u;
  unsigned short widx[64][8];   // 0xFFFF sentinel for '_'
  unsigned char  pidx[64][8];
  unsigned char  didx[64][8];
  float bo_l[96];
};  // total 51,584 B -> 2 blocks/CU

__launch_bounds__(512, 4)
__global__ void dp_main(const int* __restrict__ word_idx,
                        const int* __restrict__ pos_idx,
                        const int* __restrict__ dep_idx,
                        const float* __restrict__ word_table,
                        const unsigned short* __restrict__ WB,
                        const unsigned short* __restrict__ WoP,
                        const float* __restrict__ bo,
                        float* __restrict__ out) {
  __shared__ SMem sm;
  const int tid = threadIdx.x;
  const int lane = tid & 63;
  const int w = tid >> 6;
  const int blockRow = blockIdx.x * BM;

  // ---- stage indices ----
  if (tid < 448) {
    int r = tid / 7, t = tid - r*7;
    int g = (blockRow + r)*7 + t;
    int wi = word_idx[g];
    sm.widx[r][t] = (wi < 0) ? 0xFFFFu : (unsigned short)wi;
    sm.pidx[r][t] = (unsigned char)pos_idx[g];
    sm.didx[r][t] = (unsigned char)dep_idx[g];
  }
  if (tid < 96) sm.bo_l[tid] = (tid < OUTC) ? bo[tid] : 0.f;

  // A-write thread mapping: 512 threads cover 4 mtiles x 64 lanes x 2 halves
  const int amt   = tid >> 7;
  const int alane = (tid >> 1) & 63;
  const int ahalf = tid & 1;
  const int arow  = amt*16 + (alane & 15);
  const int ak    = ((alane >> 4) << 3) + ahalf*4;   // k offset within 32-step

  const int mtb = (w >> 2) * 2;     // waves 0-3 -> mtiles 0,1 ; 4-7 -> 2,3
  const int ntb = (w & 3) * 11;     // 11 n-tiles per wave

  f32x4 acc0[11], acc1[11];
#pragma unroll
  for (int j = 0; j < 11; ++j) { acc0[j] = (f32x4){0,0,0,0}; acc1[j] = (f32x4){0,0,0,0}; }

  // ---- helpers ----
  auto issueB = [&](int ks) {
    const unsigned short* src = WB + (size_t)ks*(NTT*64*8);
#pragma unroll
    for (int it = 0; it < 6; ++it) {
      int slot = it*512 + tid;
      if (slot < NTT*64) {
        __builtin_amdgcn_global_load_lds(
            (const __attribute__((address_space(1))) unsigned int*)(src + slot*8),
            (__attribute__((address_space(3))) unsigned int*)(sm.u.mm.B + slot*8),
            16, 0, 0);
      }
    }
  };
  // stage1: issue gather load (word region) or build one-hot bits (VALU only)
  auto stage1 = [&](int ks, float4& g) {
    int k0 = ks*32 + ak;
    g = make_float4(0.f, 0.f, 0.f, 0.f);
    if (k0 < 700) {
      int t = k0/100, d = k0 - t*100;               // d mult of 4, never straddles row
      unsigned wi = sm.widx[arow][t];
      if (wi != 0xFFFFu) g = *(const float4*)(word_table + (size_t)wi*100 + d);
    } else {
      unsigned short r_[4];
#pragma unroll
      for (int j = 0; j < 4; ++j) {
        int k = k0 + j;
        unsigned short rv = 0;
        if (k < 1050) {
          int u = k - 700; int t = u/50; int pp = u - t*50;
          if (pp == (int)sm.pidx[arow][t]) rv = 0x3F80;
        } else if (k < 1365) {
          int u = k - 1050; int t = u/45; int dd = u - t*45;
          if (dd == (int)sm.didx[arow][t]) rv = 0x3F80;
        } else if (k == 1365) rv = 0x3F80;
        r_[j] = rv;
      }
      g.x = __uint_as_float((unsigned)r_[0] | ((unsigned)r_[1] << 16));
      g.y = __uint_as_float((unsigned)r_[2] | ((unsigned)r_[3] << 16));
    }
  };
  auto stage2 = [&](int ks, float4 g) {
    int k0 = ks*32 + ak;
    unsigned v0, v1;
    if (k0 < 700) {
      v0 = (unsigned)f2bf(g.x) | ((unsigned)f2bf(g.y) << 16);
      v1 = (unsigned)f2bf(g.z) | ((unsigned)f2bf(g.w) << 16);
    } else {
      v0 = __float_as_uint(g.x);
      v1 = __float_as_uint(g.y);
    }
    uint2 pk; pk.x = v0; pk.y = v1;
    *(uint2*)(sm.u.mm.A + ((amt*64 + alane)*8 + ahalf*4)) = pk;
  };
  auto compute = [&]() {
    const bf16x8* Af = (const bf16x8*)sm.u.mm.A;
    const bf16x8* Bf = (const bf16x8*)sm.u.mm.B;
    bf16x8 a0 = Af[(mtb + 0)*64 + lane];
    bf16x8 a1 = Af[(mtb + 1)*64 + lane];
#pragma unroll
    for (int j = 0; j < 11; ++j) {
      bf16x8 b = Bf[(ntb + j)*64 + lane];
      acc0[j] = __builtin_amdgcn_mfma_f32_16x16x32_bf16(a0, b, acc0[j], 0, 0, 0);
      acc1[j] = __builtin_amdgcn_mfma_f32_16x16x32_bf16(a1, b, acc1[j], 0, 0, 0);
    }
  };

  // ---- prologue ----
  issueB(0);
  __syncthreads();                 // widx visible (also drains B(0))
  {
    float4 g; stage1(0, g); stage2(0, g);
  }
  __syncthreads();                 // A(0) visible

  // ---- main K loop: 43 steps, single-buffered A/B, T14 gather split ----
  for (int ks = 0; ks < KSTEPS; ++ks) {
    float4 gn;
    const bool pre = (ks + 1 < KSTEPS);
    if (pre) stage1(ks + 1, gn);   // global loads / one-hot VALU issued early
    compute();
    __syncthreads();               // A(ks)/B(ks) fully consumed
    if (pre) { issueB(ks + 1); stage2(ks + 1, gn); }
    __syncthreads();               // drains B vmcnt + A ds_writes
  }

  // ---- epilogue: cube + second GEMM (N=96,K=704) in two half-K phases ----
  f32x4 c2[3];
#pragma unroll
  for (int jn = 0; jn < 3; ++jn) c2[jn] = (f32x4){0,0,0,0};
  const int mt2 = w >> 1;
  const int nb2 = (w & 1)*3;
  const int arow2 = mt2*16 + (lane & 15);
  const int koff2 = (lane >> 4)*8;
  const bf16x8* WoF = (const bf16x8*)WoP;
  const int myph = (w & 3) >> 1;   // which phase this wave's h-columns belong to
  const int lr = ((lane >> 4) << 2), lc = lane & 15;

#pragma unroll
  for (int ph = 0; ph < 2; ++ph) {
    if (myph == ph) {
      int cbase = ntb*16 - ph*352;
#pragma unroll
      for (int j = 0; j < 11; ++j) {
#pragma unroll
        for (int r = 0; r < 4; ++r) {
          float h0 = acc0[j][r];
          float h1 = acc1[j][r];
          sm.u.h3h[((mtb+0)*16 + lr + r)*H3S + cbase + j*16 + lc] = f2bf(h0*h0*h0);
          sm.u.h3h[((mtb+1)*16 + lr + r)*H3S + cbase + j*16 + lc] = f2bf(h1*h1*h1);
        }
      }
    }
    __syncthreads();
    // all waves: partial second GEMM over this half's 11 k-steps
#pragma unroll 2
    for (int ksl = 0; ksl < 11; ++ksl) {
      bf16x8 a = *(const bf16x8*)(sm.u.h3h + arow2*H3S + ksl*32 + koff2);
      int ks2 = ph*11 + ksl;
#pragma unroll
      for (int jn = 0; jn < 3; ++jn) {
        bf16x8 b = WoF[(size_t)(ks2*6 + nb2 + jn)*64 + lane];
        c2[jn] = __builtin_amdgcn_mfma_f32_16x16x32_bf16(a, b, c2[jn], 0, 0, 0);
      }
    }
    __syncthreads();
  }

  // ---- logits to LDS (reuse h3h region), then softmax ----
  {
    float* lg = (float*)sm.u.h3h;
#pragma unroll
    for (int jn = 0; jn < 3; ++jn)
#pragma unroll
      for (int r = 0; r < 4; ++r)
        lg[(mt2*16 + lr + r)*96 + (nb2 + jn)*16 + lc] = c2[jn][r];
  }
  __syncthreads();
  {
    const float* lg = (const float*)sm.u.h3h;
    int row = tid >> 3, s = tid & 7;
    const float4* lp = (const float4*)(lg + row*96 + s*12);
    float4 xa = lp[0], xb = lp[1], xc = lp[2];
    float x[12] = {xa.x,xa.y,xa.z,xa.w, xb.x,xb.y,xb.z,xb.w, xc.x,xc.y,xc.z,xc.w};
    int cb = s*12;
    float mx = -1e30f;
#pragma unroll
    for (int i = 0; i < 12; ++i) {
      int c = cb + i;
      x[i] += sm.bo_l[c];
      mx = fmaxf(mx, (c < OUTC) ? x[i] : -1e30f);
    }
    mx = fmaxf(mx, __shfl_xor(mx, 1, 8));
    mx = fmaxf(mx, __shfl_xor(mx, 2, 8));
    mx = fmaxf(mx, __shfl_xor(mx, 4, 8));
    float e[12]; float sum = 0.f;
#pragma unroll
    for (int i = 0; i < 12; ++i) {
      int c = cb + i;
      e[i] = (c < OUTC) ? __expf(x[i] - mx) : 0.f;
      sum += e[i];
    }
    sum += __shfl_xor(sum, 1, 8);
    sum += __shfl_xor(sum, 2, 8);
    sum += __shfl_xor(sum, 4, 8);
    float inv = 1.0f / sum;
    float* op = out + (size_t)(blockRow + row)*OUTC;
#pragma unroll
    for (int i = 0; i < 12; ++i) {
      int c = cb + i;
      if (c < OUTC) op[c] = e[i]*inv;
    }
  }
}

extern "C" void kernel_launch(void* const* d_in, const int* in_sizes, int n_in,
                              void* d_out, int out_size, void* d_ws, size_t ws_size,
                              hipStream_t stream) {
  const int*   word_idx   = (const int*)d_in[0];
  const int*   pos_idx    = (const int*)d_in[1];
  const int*   dep_idx    = (const int*)d_in[2];
  const float* word_table = (const float*)d_in[3];
  const float* pos_table  = (const float*)d_in[4];
  const float* dep_table  = (const float*)d_in[5];
  const float* Ww = (const float*)d_in[6];
  const float* bw = (const float*)d_in[7];
  const float* Wp = (const float*)d_in[8];
  const float* bp = (const float*)d_in[9];
  const float* Wd = (const float*)d_in[10];
  const float* bd = (const float*)d_in[11];
  const float* Wo = (const float*)d_in[12];
  const float* bo = (const float*)d_in[13];
  float* out = (float*)d_out;

  char* ws = (char*)d_ws;
  unsigned short* WBp = (unsigned short*)(ws + O_WB);
  unsigned short* WoP = (unsigned short*)(ws + O_WOP);

  build_WB<<<KSTEPS*11, 256, 0, stream>>>(Ww, Wp, Wd, pos_table, dep_table, bw, bp, bd, WBp);
  pack_w<<<KS2*6, 64, 0, stream>>>(Wo, WoP, 700, OUTC, 6);
  dp_main<<<65536/BM, 512, 0, stream>>>(word_idx, pos_idx, dep_idx, word_table,
                                        WBp, WoP, bo, out);
}